// Round 17
// baseline (134.039 us; speedup 1.0000x reference)
//
#include <hip/hip_runtime.h>

constexpr int DIN  = 128;
constexpr int DOUT = 128;
constexpr float EPS_SCALE = 1e-7f;
constexpr int BN = 128;            // nodes per bucket (region <= ~32KB)
constexpr int MAXNB = 512;

typedef __attribute__((ext_vector_type(8))) short bf16x8;
typedef __attribute__((ext_vector_type(4))) float f32x4;
typedef __attribute__((ext_vector_type(2))) float f32x2;

__device__ __forceinline__ float lrelu(float x) { return fmaxf(x, 0.01f * x); }

__device__ __forceinline__ unsigned short f2bf(float x) {
    unsigned u = __float_as_uint(x);
    unsigned r = (u + 0x7FFFu + ((u >> 16) & 1u)) >> 16;   // RNE
    return (unsigned short)r;
}
__device__ __forceinline__ float bf2f(unsigned short h) {
    return __uint_as_float(((unsigned)h) << 16);
}

// ---------------------------------------------------------------------------
// 1) Fused prep: bucket-count(dst) | feat fp32->bf16 | pack W frags + bias +
//    W_spatial SoA | pos4.
// ---------------------------------------------------------------------------
__global__ __launch_bounds__(256) void prep_kernel(
    const int* __restrict__ dst, int* __restrict__ bucketCnt, int E, int b2,
    int NB,
    const float* __restrict__ feat, unsigned short* __restrict__ featbf,
    int total8, int cb,
    const float* __restrict__ Wself, const float* __restrict__ Wneigh,
    const float* __restrict__ b_self, const float* __restrict__ b_neigh,
    const float* __restrict__ bias,
    unsigned short* __restrict__ bfrag, float* __restrict__ bb,
    const float* __restrict__ Wsp, float* __restrict__ wsoa, int pb,
    const float* __restrict__ pos, float4* __restrict__ pos4, int N)
{
    int b = blockIdx.x;
    int tid = threadIdx.x;
    if (b < b2) {
        __shared__ int cnt[MAXNB];
        for (int i = tid; i < NB; i += 256) cnt[i] = 0;
        __syncthreads();
        int e0 = b * 1024 + tid * 4;
        if (e0 + 3 < E) {
            int4 d4 = *(const int4*)(dst + e0);
            atomicAdd(&cnt[d4.x >> 7], 1);
            atomicAdd(&cnt[d4.y >> 7], 1);
            atomicAdd(&cnt[d4.z >> 7], 1);
            atomicAdd(&cnt[d4.w >> 7], 1);
        } else {
            for (int j = 0; j < 4; ++j)
                if (e0 + j < E) atomicAdd(&cnt[dst[e0 + j] >> 7], 1);
        }
        __syncthreads();
        for (int i = tid; i < NB; i += 256)
            if (cnt[i]) atomicAdd(&bucketCnt[i], cnt[i]);
    } else if (b < b2 + cb) {
        int i = (b - b2) * 256 + tid;          // handles 8 floats
        if (i < total8) {
            float4 v0 = *(const float4*)(feat + (size_t)i * 8);
            float4 v1 = *(const float4*)(feat + (size_t)i * 8 + 4);
            bf16x8 o;
            o[0] = (short)f2bf(v0.x); o[1] = (short)f2bf(v0.y);
            o[2] = (short)f2bf(v0.z); o[3] = (short)f2bf(v0.w);
            o[4] = (short)f2bf(v1.x); o[5] = (short)f2bf(v1.y);
            o[6] = (short)f2bf(v1.z); o[7] = (short)f2bf(v1.w);
            *(bf16x8*)(featbf + (size_t)i * 8) = o;
        }
    } else if (b < b2 + cb + pb) {
        int idx = (b - b2 - cb) * 256 + tid;   // 0..32767
        if (idx < 32768) {
            int j = idx & 7;
            int l = (idx >> 3) & 63;
            int f = (idx >> 9) & 7;
            int s = (idx >> 12) & 7;
            int k = s * 32 + ((l >> 4) << 3) + j;
            int c = f * 16 + (l & 15);
            float v = (k < 128) ? Wself[c * 128 + k] : Wneigh[c * 128 + (k - 128)];
            bfrag[idx] = f2bf(v);
        }
        if (idx < 128) bb[idx] = b_self[idx] + b_neigh[idx] + bias[idx];
        if (idx < 384) {
            int r = idx >> 7, dd = idx & 127;
            wsoa[idx] = Wsp[dd * 3 + r];       // wsoa[r][d]
        }
    } else {
        int i = (b - b2 - cb - pb) * 256 + tid;
        if (i < N) {
            pos4[i] = make_float4(pos[i * 3 + 0], pos[i * 3 + 1],
                                  pos[i * 3 + 2], 0.0f);
        }
    }
}

// ---------------------------------------------------------------------------
// 2) Bucket exclusive scan (1 block of 512; NB <= 512). rowptr[N]=E sentinel.
// ---------------------------------------------------------------------------
__global__ __launch_bounds__(512) void bucket_scan(
    const int* __restrict__ bucketCnt, int* __restrict__ bucketBase, int NB,
    int* __restrict__ rowptr, int N, int E)
{
    __shared__ int wsum[8];
    int tid = threadIdx.x, lane = tid & 63, w = tid >> 6;
    int v = (tid < NB) ? bucketCnt[tid] : 0;
    int x = v;
#pragma unroll
    for (int off = 1; off < 64; off <<= 1) {
        int t = __shfl_up(x, off, 64);
        if (lane >= off) x += t;
    }
    if (lane == 63) wsum[w] = x;
    __syncthreads();
    int add = 0;
#pragma unroll
    for (int ww = 0; ww < 8; ++ww) if (ww < w) add += wsum[ww];
    if (tid < NB) bucketBase[tid] = add + x - v;
    if (tid == 0) { bucketBase[NB] = E; rowptr[N] = E; }
}

// ---------------------------------------------------------------------------
// 3) binA: bucket-partition edges. LDS slot assignment + one chunk
//    reservation per (block,bucket). Coeffs from pos4. Dense chunk writes.
//    Record: {c0, c1, c2, (src<<16)|dst}
// ---------------------------------------------------------------------------
__global__ __launch_bounds__(256) void binA_kernel(
    const int* __restrict__ dst, const int* __restrict__ src,
    const float4* __restrict__ pos4, const int* __restrict__ bucketBase,
    int* __restrict__ gcur, uint4* __restrict__ etmp, int E, int NB)
{
    __shared__ int cnt[MAXNB];
    __shared__ int cbase[MAXNB];
    int tid = threadIdx.x;
    for (int i = tid; i < NB; i += 256) cnt[i] = 0;
    __syncthreads();

    int e0 = blockIdx.x * 1024 + tid * 4;
    int dd[4], ss[4], slot[4];
    float cc[4][3];
    int nv = min(4, E - e0);            // valid edges this thread (may be <=0)
    if (nv > 0 && nv == 4) {
        int4 d4 = *(const int4*)(dst + e0);
        int4 s4 = *(const int4*)(src + e0);
        dd[0] = d4.x; dd[1] = d4.y; dd[2] = d4.z; dd[3] = d4.w;
        ss[0] = s4.x; ss[1] = s4.y; ss[2] = s4.z; ss[3] = s4.w;
    } else if (nv > 0) {
#pragma unroll
        for (int j = 0; j < 4; ++j) {
            dd[j] = (j < nv) ? dst[e0 + j] : 0;
            ss[j] = (j < nv) ? src[e0 + j] : 0;
        }
    }
    if (nv > 0) {
#pragma unroll
        for (int j = 0; j < 4; ++j) {
            if (j < nv) {
                slot[j] = atomicAdd(&cnt[dd[j] >> 7], 1);
                float4 pd = pos4[dd[j]];
                float4 ps = pos4[ss[j]];
                float r0 = pd.x - ps.x;
                float r1 = pd.y - ps.y;
                float r2 = pd.z - ps.z;
                float inv = 1.0f / (sqrtf(r0 * r0 + r1 * r1 + r2 * r2) + EPS_SCALE);
                cc[j][0] = (r0 + 1.0f) * inv;
                cc[j][1] = (r1 + 1.0f) * inv;
                cc[j][2] = (r2 + 1.0f) * inv;
            }
        }
    }
    __syncthreads();
    for (int i = tid; i < NB; i += 256)
        cbase[i] = cnt[i] ? atomicAdd(&gcur[i], cnt[i]) : 0;
    __syncthreads();
    if (nv > 0) {
#pragma unroll
        for (int j = 0; j < 4; ++j) {
            if (j < nv) {
                int bk = dd[j] >> 7;
                int p = bucketBase[bk] + cbase[bk] + slot[j];
                etmp[p] = make_uint4(__float_as_uint(cc[j][0]),
                                     __float_as_uint(cc[j][1]),
                                     __float_as_uint(cc[j][2]),
                                     ((unsigned)ss[j] << 16) | (unsigned)dd[j]);
            }
        }
    }
}

// ---------------------------------------------------------------------------
// 4) binB: one block per bucket. Node counts, scan, cursors all in LDS
//    (zero global atomics). Emits rowptr + node-ordered ecoef.
// ---------------------------------------------------------------------------
__global__ __launch_bounds__(256) void binB_kernel(
    const uint4* __restrict__ etmp, const int* __restrict__ bucketBase,
    float4* __restrict__ ecoef, int* __restrict__ rowptr, int N)
{
    __shared__ int ncnt[BN];
    __shared__ int noff[BN];
    __shared__ int wsum[4];
    int b = blockIdx.x, tid = threadIdx.x;
    int start = bucketBase[b];
    int endb  = bucketBase[b + 1];

    if (tid < BN) ncnt[tid] = 0;
    __syncthreads();
    for (int i = start + tid; i < endb; i += 256)
        atomicAdd(&ncnt[etmp[i].w & (BN - 1)], 1);
    __syncthreads();

    int lane = tid & 63, w = tid >> 6;
    int v = (tid < BN) ? ncnt[tid] : 0;
    int x = v;
#pragma unroll
    for (int off = 1; off < 64; off <<= 1) {
        int t = __shfl_up(x, off, 64);
        if (lane >= off) x += t;
    }
    if (lane == 63) wsum[w] = x;
    __syncthreads();
    int add = 0;
#pragma unroll
    for (int ww = 0; ww < 4; ++ww) if (ww < w) add += wsum[ww];
    int excl = add + x - v;
    if (tid < BN) {
        noff[tid] = excl;
        int node = b * BN + tid;
        if (node < N) rowptr[node] = start + excl;
    }
    __syncthreads();

    for (int i = start + tid; i < endb; i += 256) {
        uint4 r = etmp[i];
        int dl = (int)(r.w & (BN - 1));
        int p = atomicAdd(&noff[dl], 1);
        ecoef[start + p] = make_float4(__uint_as_float(r.x),
                                       __uint_as_float(r.y),
                                       __uint_as_float(r.z),
                                       __int_as_float((int)(r.w >> 16)));
    }
}

// ---------------------------------------------------------------------------
// 5) Gather: 2 nodes/wave, 2 edge slots/node, 3x unroll -> 12 chains/wave.
//    Packed f32x2 math (pk_fma). sl owns dims sl*8..sl*8+7.
// ---------------------------------------------------------------------------
#define EDGE_FMA2(QC, FU)                                                        \
    do {                                                                         \
        f32x2 c0v = {QC.x, QC.x};                                                \
        f32x2 c1v = {QC.y, QC.y};                                                \
        f32x2 c2v = {QC.z, QC.z};                                                \
        unsigned fw0 = FU.x, fw1 = FU.y, fw2 = FU.z, fw3 = FU.w;                 \
        f32x2 fv0 = {__uint_as_float(fw0 << 16),                                 \
                     __uint_as_float(fw0 & 0xffff0000u)};                        \
        f32x2 fv1 = {__uint_as_float(fw1 << 16),                                 \
                     __uint_as_float(fw1 & 0xffff0000u)};                        \
        f32x2 fv2 = {__uint_as_float(fw2 << 16),                                 \
                     __uint_as_float(fw2 & 0xffff0000u)};                        \
        f32x2 fv3 = {__uint_as_float(fw3 << 16),                                 \
                     __uint_as_float(fw3 & 0xffff0000u)};                        \
        f32x2 g0 = __builtin_elementwise_fma(c0v, w0v[0],                        \
                   __builtin_elementwise_fma(c1v, w1v[0],                        \
                   __builtin_elementwise_fma(c2v, w2v[0], bv[0])));              \
        f32x2 g1 = __builtin_elementwise_fma(c0v, w0v[1],                        \
                   __builtin_elementwise_fma(c1v, w1v[1],                        \
                   __builtin_elementwise_fma(c2v, w2v[1], bv[1])));              \
        f32x2 g2 = __builtin_elementwise_fma(c0v, w0v[2],                        \
                   __builtin_elementwise_fma(c1v, w1v[2],                        \
                   __builtin_elementwise_fma(c2v, w2v[2], bv[2])));              \
        f32x2 g3 = __builtin_elementwise_fma(c0v, w0v[3],                        \
                   __builtin_elementwise_fma(c1v, w1v[3],                        \
                   __builtin_elementwise_fma(c2v, w2v[3], bv[3])));              \
        g0 = __builtin_elementwise_max(g0, g0 * 0.01f);                          \
        g1 = __builtin_elementwise_max(g1, g1 * 0.01f);                          \
        g2 = __builtin_elementwise_max(g2, g2 * 0.01f);                          \
        g3 = __builtin_elementwise_max(g3, g3 * 0.01f);                          \
        acc[0] = __builtin_elementwise_fma(g0, fv0, acc[0]);                     \
        acc[1] = __builtin_elementwise_fma(g1, fv1, acc[1]);                     \
        acc[2] = __builtin_elementwise_fma(g2, fv2, acc[2]);                     \
        acc[3] = __builtin_elementwise_fma(g3, fv3, acc[3]);                     \
    } while (0)

__global__ __launch_bounds__(256) void gather_kernel(
    const unsigned short* __restrict__ featbf,
    const float4* __restrict__ ecoef,
    const int*   __restrict__ rowptr,
    const float* __restrict__ wsoa,  // [3][128]
    const float* __restrict__ bsp,   // [128]
    unsigned short* __restrict__ hmbf,  // [N][128]
    int N, int nwaves)
{
    int gw   = (blockIdx.x * 256 + threadIdx.x) >> 6;
    int lane = threadIdx.x & 63;
    int half = lane >> 5;          // which node of the pair
    int e2   = (lane >> 4) & 1;    // edge slot within the node
    int sl   = lane & 15;
    int d    = sl * 8;

    f32x2 w0v[4], w1v[4], w2v[4], bv[4];
#pragma unroll
    for (int g = 0; g < 4; ++g) {
        w0v[g] = *(const f32x2*)(wsoa + d + g * 2);
        w1v[g] = *(const f32x2*)(wsoa + 128 + d + g * 2);
        w2v[g] = *(const f32x2*)(wsoa + 256 + d + g * 2);
        bv[g]  = *(const f32x2*)(bsp + d + g * 2);
    }

    const unsigned short* fb = featbf + d;
    int stride = nwaves * 2;

    for (int vp = gw * 2; vp < N; vp += stride) {
        int v = vp + half;
        int start = 0, end = 0;
        if (v < N) { start = rowptr[v]; end = rowptr[v + 1]; }

        f32x2 acc[4];
#pragma unroll
        for (int g = 0; g < 4; ++g) acc[g] = (f32x2)0.0f;

        int i = start + e2;
        // Triples: edges i, i+2, i+4 — all loads issued before compute.
        for (; i + 4 < end; i += 6) {
            float4 qcA = ecoef[i];
            float4 qcB = ecoef[i + 2];
            float4 qcC = ecoef[i + 4];
            uint4 fA = *(const uint4*)(fb + (size_t)__float_as_int(qcA.w) * DIN);
            uint4 fB = *(const uint4*)(fb + (size_t)__float_as_int(qcB.w) * DIN);
            uint4 fC = *(const uint4*)(fb + (size_t)__float_as_int(qcC.w) * DIN);
            EDGE_FMA2(qcA, fA);
            EDGE_FMA2(qcB, fB);
            EDGE_FMA2(qcC, fC);
        }
        for (; i < end; i += 2) {
            float4 qcA = ecoef[i];
            uint4 fA = *(const uint4*)(fb + (size_t)__float_as_int(qcA.w) * DIN);
            EDGE_FMA2(qcA, fA);
        }

        // combine the two edge slots (within the 32-lane half)
#pragma unroll
        for (int g = 0; g < 4; ++g) {
            acc[g].x += __shfl_xor(acc[g].x, 16);
            acc[g].y += __shfl_xor(acc[g].y, 16);
        }

        if (e2 == 0 && v < N) {
            float invd = 1.0f / fmaxf((float)(end - start), 1.0f);
            bf16x8 o;
#pragma unroll
            for (int g = 0; g < 4; ++g) {
                o[g * 2 + 0] = (short)f2bf(acc[g].x * invd);
                o[g * 2 + 1] = (short)f2bf(acc[g].y * invd);
            }
            *(bf16x8*)(hmbf + (size_t)v * DIN + d) = o;
        }
    }
}

// ---------------------------------------------------------------------------
// 6) Node GEMM via MFMA: out = lrelu([featbf | hmbf] @ Wc^T + bb)
// ---------------------------------------------------------------------------
__global__ __launch_bounds__(256) void node_mfma_kernel(
    const unsigned short* __restrict__ featbf,
    const unsigned short* __restrict__ hmbf,
    const unsigned short* __restrict__ bfrag,
    const float* __restrict__ bb,
    float* __restrict__ out, int N)
{
    int wave = threadIdx.x >> 6;
    int lane = threadIdx.x & 63;
    int r0   = blockIdx.x * 64 + wave * 16;
    int row  = r0 + (lane & 15);
    bool rowok = row < N;
    int kb = (lane >> 4) << 3;

    f32x4 acc[8];
#pragma unroll
    for (int f = 0; f < 8; ++f) acc[f] = (f32x4)0.0f;

#pragma unroll
    for (int s = 0; s < 8; ++s) {
        bf16x8 a = (bf16x8)(short)0;
        if (rowok) {
            const unsigned short* base =
                (s < 4 ? featbf : hmbf) + (size_t)row * DIN + (s & 3) * 32 + kb;
            a = *(const bf16x8*)base;
        }
#pragma unroll
        for (int f = 0; f < 8; ++f) {
            bf16x8 b = *(const bf16x8*)(bfrag + ((((s * 8 + f) * 64) + lane) * 8));
            acc[f] = __builtin_amdgcn_mfma_f32_16x16x32_bf16(a, b, acc[f], 0, 0, 0);
        }
    }

    int crow = r0 + ((lane >> 4) << 2);
    int col  = lane & 15;
#pragma unroll
    for (int f = 0; f < 8; ++f) {
        int c = f * 16 + col;
        float bbv = bb[c];
#pragma unroll
        for (int r = 0; r < 4; ++r) {
            int rr = crow + r;
            if (rr < N) out[(size_t)rr * DOUT + c] = lrelu(acc[f][r] + bbv);
        }
    }
}

// ---------------------------------------------------------------------------
extern "C" void kernel_launch(void* const* d_in, const int* in_sizes, int n_in,
                              void* d_out, int out_size, void* d_ws, size_t ws_size,
                              hipStream_t stream)
{
    const float* feat    = (const float*)d_in[0];
    const float* pos     = (const float*)d_in[1];
    const int*   src     = (const int*)  d_in[2];
    const int*   dst     = (const int*)  d_in[3];
    const float* Wsp     = (const float*)d_in[4];
    const float* bsp     = (const float*)d_in[5];
    const float* Wneigh  = (const float*)d_in[6];
    const float* b_neigh = (const float*)d_in[7];
    const float* Wself   = (const float*)d_in[8];
    const float* b_self  = (const float*)d_in[9];
    const float* bias    = (const float*)d_in[10];

    int N = in_sizes[0] / DIN;
    int E = in_sizes[2];
    int NB = (N + BN - 1) / BN;   // buckets (391 for N=50000; <= 512)

    // Workspace layout (all 16B aligned):
    // featbf [N*128 u16] | hmbf [N*128 u16] | ecoef [E f4] | etmp [E u4]
    // | pos4 [N f4] | bfrag [32768 u16] | bb [128 f32] | wsoa [384 f32]
    // | bucketCnt [512] | gcur [512] | bucketBase [520] | rowptr [N+4]
    char* p = (char*)d_ws;
    unsigned short* featbf = (unsigned short*)p; p += (size_t)N * DIN * 2;
    unsigned short* hmbf   = (unsigned short*)p; p += (size_t)N * DIN * 2;
    float4* ecoef          = (float4*)p;         p += (size_t)E * 16;
    uint4* etmp            = (uint4*)p;          p += (size_t)E * 16;
    float4* pos4           = (float4*)p;         p += (size_t)N * 16;
    unsigned short* bfrag  = (unsigned short*)p; p += 32768 * 2;
    float* bb              = (float*)p;          p += 128 * 4;
    float* wsoa            = (float*)p;          p += 384 * 4;
    int* bucketCnt         = (int*)p;            p += 512 * 4;
    int* gcur              = (int*)p;            p += 512 * 4;
    int* bucketBase        = (int*)p;            p += 520 * 4;
    int* rowptr            = (int*)p;

    // zero bucketCnt + gcur (adjacent, 4KB)
    hipMemsetAsync(bucketCnt, 0, 1024 * sizeof(int), stream);

    int b2 = (E + 1023) / 1024;          // bucket-count / binA blocks
    int cb = (N * 16 + 255) / 256;       // convert blocks (N*128/8 threads)
    int pb = 129;                        // pack blocks
    int qb = (N + 255) / 256;            // pos4 blocks
    prep_kernel<<<b2 + cb + pb + qb, 256, 0, stream>>>(
        dst, bucketCnt, E, b2, NB, feat, featbf, N * 16, cb,
        Wself, Wneigh, b_self, b_neigh, bias, bfrag, bb, Wsp, wsoa, pb,
        pos, pos4, N);

    bucket_scan<<<1, 512, 0, stream>>>(bucketCnt, bucketBase, NB, rowptr, N, E);

    binA_kernel<<<b2, 256, 0, stream>>>(dst, src, pos4, bucketBase, gcur,
                                        etmp, E, NB);
    binB_kernel<<<NB, 256, 0, stream>>>(etmp, bucketBase, ecoef, rowptr, N);

    int gblocks = 2048;
    gather_kernel<<<gblocks, 256, 0, stream>>>(featbf, ecoef, rowptr, wsoa, bsp,
                                               hmbf, N, gblocks * 4);

    node_mfma_kernel<<<(N + 63) / 64, 256, 0, stream>>>(featbf, hmbf, bfrag, bb,
                                                        (float*)d_out, N);
}

// Round 18
// 131.137 us; speedup vs baseline: 1.0221x; 1.0221x over previous
//
#include <hip/hip_runtime.h>

constexpr int DIN  = 128;
constexpr int DOUT = 128;
constexpr float EPS_SCALE = 1e-7f;
constexpr int BN = 128;            // nodes per bucket (region <= ~32KB)
constexpr int MAXNB = 512;

typedef __attribute__((ext_vector_type(8))) short bf16x8;
typedef __attribute__((ext_vector_type(4))) float f32x4;
typedef __attribute__((ext_vector_type(2))) float f32x2;

__device__ __forceinline__ float lrelu(float x) { return fmaxf(x, 0.01f * x); }

__device__ __forceinline__ unsigned short f2bf(float x) {
    unsigned u = __float_as_uint(x);
    unsigned r = (u + 0x7FFFu + ((u >> 16) & 1u)) >> 16;   // RNE
    return (unsigned short)r;
}
__device__ __forceinline__ float bf2f(unsigned short h) {
    return __uint_as_float(((unsigned)h) << 16);
}

// ---------------------------------------------------------------------------
// 1) Fused prep: bucket-count(dst) | feat fp32->bf16 | pack W frags + bias +
//    W_spatial SoA | pos4.
// ---------------------------------------------------------------------------
__global__ __launch_bounds__(256) void prep_kernel(
    const int* __restrict__ dst, int* __restrict__ bucketCnt, int E, int b2,
    int NB,
    const float* __restrict__ feat, unsigned short* __restrict__ featbf,
    int total8, int cb,
    const float* __restrict__ Wself, const float* __restrict__ Wneigh,
    const float* __restrict__ b_self, const float* __restrict__ b_neigh,
    const float* __restrict__ bias,
    unsigned short* __restrict__ bfrag, float* __restrict__ bb,
    const float* __restrict__ Wsp, float* __restrict__ wsoa, int pb,
    const float* __restrict__ pos, float4* __restrict__ pos4, int N)
{
    int b = blockIdx.x;
    int tid = threadIdx.x;
    if (b < b2) {
        __shared__ int cnt[MAXNB];
        for (int i = tid; i < NB; i += 256) cnt[i] = 0;
        __syncthreads();
        int e0 = b * 1024 + tid * 4;
        if (e0 + 3 < E) {
            int4 d4 = *(const int4*)(dst + e0);
            atomicAdd(&cnt[d4.x >> 7], 1);
            atomicAdd(&cnt[d4.y >> 7], 1);
            atomicAdd(&cnt[d4.z >> 7], 1);
            atomicAdd(&cnt[d4.w >> 7], 1);
        } else {
            for (int j = 0; j < 4; ++j)
                if (e0 + j < E) atomicAdd(&cnt[dst[e0 + j] >> 7], 1);
        }
        __syncthreads();
        for (int i = tid; i < NB; i += 256)
            if (cnt[i]) atomicAdd(&bucketCnt[i], cnt[i]);
    } else if (b < b2 + cb) {
        int i = (b - b2) * 256 + tid;          // handles 8 floats
        if (i < total8) {
            float4 v0 = *(const float4*)(feat + (size_t)i * 8);
            float4 v1 = *(const float4*)(feat + (size_t)i * 8 + 4);
            bf16x8 o;
            o[0] = (short)f2bf(v0.x); o[1] = (short)f2bf(v0.y);
            o[2] = (short)f2bf(v0.z); o[3] = (short)f2bf(v0.w);
            o[4] = (short)f2bf(v1.x); o[5] = (short)f2bf(v1.y);
            o[6] = (short)f2bf(v1.z); o[7] = (short)f2bf(v1.w);
            *(bf16x8*)(featbf + (size_t)i * 8) = o;
        }
    } else if (b < b2 + cb + pb) {
        int idx = (b - b2 - cb) * 256 + tid;   // 0..32767
        if (idx < 32768) {
            int j = idx & 7;
            int l = (idx >> 3) & 63;
            int f = (idx >> 9) & 7;
            int s = (idx >> 12) & 7;
            int k = s * 32 + ((l >> 4) << 3) + j;
            int c = f * 16 + (l & 15);
            float v = (k < 128) ? Wself[c * 128 + k] : Wneigh[c * 128 + (k - 128)];
            bfrag[idx] = f2bf(v);
        }
        if (idx < 128) bb[idx] = b_self[idx] + b_neigh[idx] + bias[idx];
        if (idx < 384) {
            int r = idx >> 7, dd = idx & 127;
            wsoa[idx] = Wsp[dd * 3 + r];       // wsoa[r][d]
        }
    } else {
        int i = (b - b2 - cb - pb) * 256 + tid;
        if (i < N) {
            pos4[i] = make_float4(pos[i * 3 + 0], pos[i * 3 + 1],
                                  pos[i * 3 + 2], 0.0f);
        }
    }
}

// ---------------------------------------------------------------------------
// 2) Bucket exclusive scan (1 block of 512; NB <= 512). rowptr[N]=E sentinel.
// ---------------------------------------------------------------------------
__global__ __launch_bounds__(512) void bucket_scan(
    const int* __restrict__ bucketCnt, int* __restrict__ bucketBase, int NB,
    int* __restrict__ rowptr, int N, int E)
{
    __shared__ int wsum[8];
    int tid = threadIdx.x, lane = tid & 63, w = tid >> 6;
    int v = (tid < NB) ? bucketCnt[tid] : 0;
    int x = v;
#pragma unroll
    for (int off = 1; off < 64; off <<= 1) {
        int t = __shfl_up(x, off, 64);
        if (lane >= off) x += t;
    }
    if (lane == 63) wsum[w] = x;
    __syncthreads();
    int add = 0;
#pragma unroll
    for (int ww = 0; ww < 8; ++ww) if (ww < w) add += wsum[ww];
    if (tid < NB) bucketBase[tid] = add + x - v;
    if (tid == 0) { bucketBase[NB] = E; rowptr[N] = E; }
}

// ---------------------------------------------------------------------------
// 3) binA: bucket-partition edges. LDS slot assignment + one chunk
//    reservation per (block,bucket). Coeffs from pos4. Dense chunk writes.
//    Record: {c0, c1, c2, (src<<16)|dst}
// ---------------------------------------------------------------------------
__global__ __launch_bounds__(256) void binA_kernel(
    const int* __restrict__ dst, const int* __restrict__ src,
    const float4* __restrict__ pos4, const int* __restrict__ bucketBase,
    int* __restrict__ gcur, uint4* __restrict__ etmp, int E, int NB)
{
    __shared__ int cnt[MAXNB];
    __shared__ int cbase[MAXNB];
    int tid = threadIdx.x;
    for (int i = tid; i < NB; i += 256) cnt[i] = 0;
    __syncthreads();

    int e0 = blockIdx.x * 1024 + tid * 4;
    int dd[4], ss[4], slot[4];
    float cc[4][3];
    int nv = min(4, E - e0);            // valid edges this thread (may be <=0)
    if (nv > 0 && nv == 4) {
        int4 d4 = *(const int4*)(dst + e0);
        int4 s4 = *(const int4*)(src + e0);
        dd[0] = d4.x; dd[1] = d4.y; dd[2] = d4.z; dd[3] = d4.w;
        ss[0] = s4.x; ss[1] = s4.y; ss[2] = s4.z; ss[3] = s4.w;
    } else if (nv > 0) {
#pragma unroll
        for (int j = 0; j < 4; ++j) {
            dd[j] = (j < nv) ? dst[e0 + j] : 0;
            ss[j] = (j < nv) ? src[e0 + j] : 0;
        }
    }
    if (nv > 0) {
#pragma unroll
        for (int j = 0; j < 4; ++j) {
            if (j < nv) {
                slot[j] = atomicAdd(&cnt[dd[j] >> 7], 1);
                float4 pd = pos4[dd[j]];
                float4 ps = pos4[ss[j]];
                float r0 = pd.x - ps.x;
                float r1 = pd.y - ps.y;
                float r2 = pd.z - ps.z;
                float inv = 1.0f / (sqrtf(r0 * r0 + r1 * r1 + r2 * r2) + EPS_SCALE);
                cc[j][0] = (r0 + 1.0f) * inv;
                cc[j][1] = (r1 + 1.0f) * inv;
                cc[j][2] = (r2 + 1.0f) * inv;
            }
        }
    }
    __syncthreads();
    for (int i = tid; i < NB; i += 256)
        cbase[i] = cnt[i] ? atomicAdd(&gcur[i], cnt[i]) : 0;
    __syncthreads();
    if (nv > 0) {
#pragma unroll
        for (int j = 0; j < 4; ++j) {
            if (j < nv) {
                int bk = dd[j] >> 7;
                int p = bucketBase[bk] + cbase[bk] + slot[j];
                etmp[p] = make_uint4(__float_as_uint(cc[j][0]),
                                     __float_as_uint(cc[j][1]),
                                     __float_as_uint(cc[j][2]),
                                     ((unsigned)ss[j] << 16) | (unsigned)dd[j]);
            }
        }
    }
}

// ---------------------------------------------------------------------------
// 4) binB: one block per bucket. Node counts, scan, cursors all in LDS
//    (zero global atomics). Emits rowptr + node-ordered ecoef.
// ---------------------------------------------------------------------------
__global__ __launch_bounds__(256) void binB_kernel(
    const uint4* __restrict__ etmp, const int* __restrict__ bucketBase,
    float4* __restrict__ ecoef, int* __restrict__ rowptr, int N)
{
    __shared__ int ncnt[BN];
    __shared__ int noff[BN];
    __shared__ int wsum[4];
    int b = blockIdx.x, tid = threadIdx.x;
    int start = bucketBase[b];
    int endb  = bucketBase[b + 1];

    if (tid < BN) ncnt[tid] = 0;
    __syncthreads();
    for (int i = start + tid; i < endb; i += 256)
        atomicAdd(&ncnt[etmp[i].w & (BN - 1)], 1);
    __syncthreads();

    int lane = tid & 63, w = tid >> 6;
    int v = (tid < BN) ? ncnt[tid] : 0;
    int x = v;
#pragma unroll
    for (int off = 1; off < 64; off <<= 1) {
        int t = __shfl_up(x, off, 64);
        if (lane >= off) x += t;
    }
    if (lane == 63) wsum[w] = x;
    __syncthreads();
    int add = 0;
#pragma unroll
    for (int ww = 0; ww < 4; ++ww) if (ww < w) add += wsum[ww];
    int excl = add + x - v;
    if (tid < BN) {
        noff[tid] = excl;
        int node = b * BN + tid;
        if (node < N) rowptr[node] = start + excl;
    }
    __syncthreads();

    for (int i = start + tid; i < endb; i += 256) {
        uint4 r = etmp[i];
        int dl = (int)(r.w & (BN - 1));
        int p = atomicAdd(&noff[dl], 1);
        ecoef[start + p] = make_float4(__uint_as_float(r.x),
                                       __uint_as_float(r.y),
                                       __uint_as_float(r.z),
                                       __int_as_float((int)(r.w >> 16)));
    }
}

// ---------------------------------------------------------------------------
// 5) Gather (r16-proven optimum): 2 nodes/wave, 2 edge slots/node, 2x unroll
//    -> 8 chains/wave (measured MLP optimum). Packed f32x2 math (pk_fma).
// ---------------------------------------------------------------------------
#define EDGE_FMA2(QC, FU)                                                        \
    do {                                                                         \
        f32x2 c0v = {QC.x, QC.x};                                                \
        f32x2 c1v = {QC.y, QC.y};                                                \
        f32x2 c2v = {QC.z, QC.z};                                                \
        unsigned fw0 = FU.x, fw1 = FU.y, fw2 = FU.z, fw3 = FU.w;                 \
        f32x2 fv0 = {__uint_as_float(fw0 << 16),                                 \
                     __uint_as_float(fw0 & 0xffff0000u)};                        \
        f32x2 fv1 = {__uint_as_float(fw1 << 16),                                 \
                     __uint_as_float(fw1 & 0xffff0000u)};                        \
        f32x2 fv2 = {__uint_as_float(fw2 << 16),                                 \
                     __uint_as_float(fw2 & 0xffff0000u)};                        \
        f32x2 fv3 = {__uint_as_float(fw3 << 16),                                 \
                     __uint_as_float(fw3 & 0xffff0000u)};                        \
        f32x2 g0 = __builtin_elementwise_fma(c0v, w0v[0],                        \
                   __builtin_elementwise_fma(c1v, w1v[0],                        \
                   __builtin_elementwise_fma(c2v, w2v[0], bv[0])));              \
        f32x2 g1 = __builtin_elementwise_fma(c0v, w0v[1],                        \
                   __builtin_elementwise_fma(c1v, w1v[1],                        \
                   __builtin_elementwise_fma(c2v, w2v[1], bv[1])));              \
        f32x2 g2 = __builtin_elementwise_fma(c0v, w0v[2],                        \
                   __builtin_elementwise_fma(c1v, w1v[2],                        \
                   __builtin_elementwise_fma(c2v, w2v[2], bv[2])));              \
        f32x2 g3 = __builtin_elementwise_fma(c0v, w0v[3],                        \
                   __builtin_elementwise_fma(c1v, w1v[3],                        \
                   __builtin_elementwise_fma(c2v, w2v[3], bv[3])));              \
        g0 = __builtin_elementwise_max(g0, g0 * 0.01f);                          \
        g1 = __builtin_elementwise_max(g1, g1 * 0.01f);                          \
        g2 = __builtin_elementwise_max(g2, g2 * 0.01f);                          \
        g3 = __builtin_elementwise_max(g3, g3 * 0.01f);                          \
        acc[0] = __builtin_elementwise_fma(g0, fv0, acc[0]);                     \
        acc[1] = __builtin_elementwise_fma(g1, fv1, acc[1]);                     \
        acc[2] = __builtin_elementwise_fma(g2, fv2, acc[2]);                     \
        acc[3] = __builtin_elementwise_fma(g3, fv3, acc[3]);                     \
    } while (0)

__global__ __launch_bounds__(256) void gather_kernel(
    const unsigned short* __restrict__ featbf,
    const float4* __restrict__ ecoef,
    const int*   __restrict__ rowptr,
    const float* __restrict__ wsoa,  // [3][128]
    const float* __restrict__ bsp,   // [128]
    unsigned short* __restrict__ hmbf,  // [N][128]
    int N, int nwaves)
{
    int gw   = (blockIdx.x * 256 + threadIdx.x) >> 6;
    int lane = threadIdx.x & 63;
    int half = lane >> 5;          // which node of the pair
    int e2   = (lane >> 4) & 1;    // edge slot within the node
    int sl   = lane & 15;
    int d    = sl * 8;

    f32x2 w0v[4], w1v[4], w2v[4], bv[4];
#pragma unroll
    for (int g = 0; g < 4; ++g) {
        w0v[g] = *(const f32x2*)(wsoa + d + g * 2);
        w1v[g] = *(const f32x2*)(wsoa + 128 + d + g * 2);
        w2v[g] = *(const f32x2*)(wsoa + 256 + d + g * 2);
        bv[g]  = *(const f32x2*)(bsp + d + g * 2);
    }

    const unsigned short* fb = featbf + d;
    int stride = nwaves * 2;

    for (int vp = gw * 2; vp < N; vp += stride) {
        int v = vp + half;
        int start = 0, end = 0;
        if (v < N) { start = rowptr[v]; end = rowptr[v + 1]; }

        f32x2 acc[4];
#pragma unroll
        for (int g = 0; g < 4; ++g) acc[g] = (f32x2)0.0f;

        int i = start + e2;
        for (; i + 2 < end; i += 4) {
            float4 qcA = ecoef[i];
            float4 qcB = ecoef[i + 2];
            uint4 fA = *(const uint4*)(fb + (size_t)__float_as_int(qcA.w) * DIN);
            uint4 fB = *(const uint4*)(fb + (size_t)__float_as_int(qcB.w) * DIN);
            EDGE_FMA2(qcA, fA);
            EDGE_FMA2(qcB, fB);
        }
        if (i < end) {
            float4 qcA = ecoef[i];
            uint4 fA = *(const uint4*)(fb + (size_t)__float_as_int(qcA.w) * DIN);
            EDGE_FMA2(qcA, fA);
        }

        // combine the two edge slots (within the 32-lane half)
#pragma unroll
        for (int g = 0; g < 4; ++g) {
            acc[g].x += __shfl_xor(acc[g].x, 16);
            acc[g].y += __shfl_xor(acc[g].y, 16);
        }

        if (e2 == 0 && v < N) {
            float invd = 1.0f / fmaxf((float)(end - start), 1.0f);
            bf16x8 o;
#pragma unroll
            for (int g = 0; g < 4; ++g) {
                o[g * 2 + 0] = (short)f2bf(acc[g].x * invd);
                o[g * 2 + 1] = (short)f2bf(acc[g].y * invd);
            }
            *(bf16x8*)(hmbf + (size_t)v * DIN + d) = o;
        }
    }
}

// ---------------------------------------------------------------------------
// 6) Node GEMM via MFMA: out = lrelu([featbf | hmbf] @ Wc^T + bb)
// ---------------------------------------------------------------------------
__global__ __launch_bounds__(256) void node_mfma_kernel(
    const unsigned short* __restrict__ featbf,
    const unsigned short* __restrict__ hmbf,
    const unsigned short* __restrict__ bfrag,
    const float* __restrict__ bb,
    float* __restrict__ out, int N)
{
    int wave = threadIdx.x >> 6;
    int lane = threadIdx.x & 63;
    int r0   = blockIdx.x * 64 + wave * 16;
    int row  = r0 + (lane & 15);
    bool rowok = row < N;
    int kb = (lane >> 4) << 3;

    f32x4 acc[8];
#pragma unroll
    for (int f = 0; f < 8; ++f) acc[f] = (f32x4)0.0f;

#pragma unroll
    for (int s = 0; s < 8; ++s) {
        bf16x8 a = (bf16x8)(short)0;
        if (rowok) {
            const unsigned short* base =
                (s < 4 ? featbf : hmbf) + (size_t)row * DIN + (s & 3) * 32 + kb;
            a = *(const bf16x8*)base;
        }
#pragma unroll
        for (int f = 0; f < 8; ++f) {
            bf16x8 b = *(const bf16x8*)(bfrag + ((((s * 8 + f) * 64) + lane) * 8));
            acc[f] = __builtin_amdgcn_mfma_f32_16x16x32_bf16(a, b, acc[f], 0, 0, 0);
        }
    }

    int crow = r0 + ((lane >> 4) << 2);
    int col  = lane & 15;
#pragma unroll
    for (int f = 0; f < 8; ++f) {
        int c = f * 16 + col;
        float bbv = bb[c];
#pragma unroll
        for (int r = 0; r < 4; ++r) {
            int rr = crow + r;
            if (rr < N) out[(size_t)rr * DOUT + c] = lrelu(acc[f][r] + bbv);
        }
    }
}

// ---------------------------------------------------------------------------
extern "C" void kernel_launch(void* const* d_in, const int* in_sizes, int n_in,
                              void* d_out, int out_size, void* d_ws, size_t ws_size,
                              hipStream_t stream)
{
    const float* feat    = (const float*)d_in[0];
    const float* pos     = (const float*)d_in[1];
    const int*   src     = (const int*)  d_in[2];
    const int*   dst     = (const int*)  d_in[3];
    const float* Wsp     = (const float*)d_in[4];
    const float* bsp     = (const float*)d_in[5];
    const float* Wneigh  = (const float*)d_in[6];
    const float* b_neigh = (const float*)d_in[7];
    const float* Wself   = (const float*)d_in[8];
    const float* b_self  = (const float*)d_in[9];
    const float* bias    = (const float*)d_in[10];

    int N = in_sizes[0] / DIN;
    int E = in_sizes[2];
    int NB = (N + BN - 1) / BN;   // buckets (391 for N=50000; <= 512)

    // Workspace layout (all 16B aligned):
    // featbf [N*128 u16] | hmbf [N*128 u16] | ecoef [E f4] | etmp [E u4]
    // | pos4 [N f4] | bfrag [32768 u16] | bb [128 f32] | wsoa [384 f32]
    // | bucketCnt [512] | gcur [512] | bucketBase [520] | rowptr [N+4]
    char* p = (char*)d_ws;
    unsigned short* featbf = (unsigned short*)p; p += (size_t)N * DIN * 2;
    unsigned short* hmbf   = (unsigned short*)p; p += (size_t)N * DIN * 2;
    float4* ecoef          = (float4*)p;         p += (size_t)E * 16;
    uint4* etmp            = (uint4*)p;          p += (size_t)E * 16;
    float4* pos4           = (float4*)p;         p += (size_t)N * 16;
    unsigned short* bfrag  = (unsigned short*)p; p += 32768 * 2;
    float* bb              = (float*)p;          p += 128 * 4;
    float* wsoa            = (float*)p;          p += 384 * 4;
    int* bucketCnt         = (int*)p;            p += 512 * 4;
    int* gcur              = (int*)p;            p += 512 * 4;
    int* bucketBase        = (int*)p;            p += 520 * 4;
    int* rowptr            = (int*)p;

    // zero bucketCnt + gcur (adjacent, 4KB)
    hipMemsetAsync(bucketCnt, 0, 1024 * sizeof(int), stream);

    int b2 = (E + 1023) / 1024;          // bucket-count / binA blocks
    int cb = (N * 16 + 255) / 256;       // convert blocks (N*128/8 threads)
    int pb = 129;                        // pack blocks
    int qb = (N + 255) / 256;            // pos4 blocks
    prep_kernel<<<b2 + cb + pb + qb, 256, 0, stream>>>(
        dst, bucketCnt, E, b2, NB, feat, featbf, N * 16, cb,
        Wself, Wneigh, b_self, b_neigh, bias, bfrag, bb, Wsp, wsoa, pb,
        pos, pos4, N);

    bucket_scan<<<1, 512, 0, stream>>>(bucketCnt, bucketBase, NB, rowptr, N, E);

    binA_kernel<<<b2, 256, 0, stream>>>(dst, src, pos4, bucketBase, gcur,
                                        etmp, E, NB);
    binB_kernel<<<NB, 256, 0, stream>>>(etmp, bucketBase, ecoef, rowptr, N);

    int gblocks = 2048;
    gather_kernel<<<gblocks, 256, 0, stream>>>(featbf, ecoef, rowptr, wsoa, bsp,
                                               hmbf, N, gblocks * 4);

    node_mfma_kernel<<<(N + 63) / 64, 256, 0, stream>>>(featbf, hmbf, bfrag, bb,
                                                        (float*)d_out, N);
}

// Round 19
// 117.218 us; speedup vs baseline: 1.1435x; 1.1187x over previous
//
#include <hip/hip_runtime.h>

constexpr int DIN  = 128;
constexpr int DOUT = 128;
constexpr float EPS_SCALE = 1e-7f;
constexpr int BN = 128;            // nodes per bucket (region <= ~32KB)
constexpr int MAXNB = 512;

typedef __attribute__((ext_vector_type(8))) short bf16x8;
typedef __attribute__((ext_vector_type(4))) float f32x4;
typedef __attribute__((ext_vector_type(2))) float f32x2;

__device__ __forceinline__ float lrelu(float x) { return fmaxf(x, 0.01f * x); }

__device__ __forceinline__ unsigned short f2bf(float x) {
    unsigned u = __float_as_uint(x);
    unsigned r = (u + 0x7FFFu + ((u >> 16) & 1u)) >> 16;   // RNE
    return (unsigned short)r;
}
__device__ __forceinline__ float bf2f(unsigned short h) {
    return __uint_as_float(((unsigned)h) << 16);
}

// ---------------------------------------------------------------------------
// 1) Fused prep: bucket-count(dst) | feat fp32->bf16 | pack W frags + bias +
//    W_spatial SoA | pos4.
// ---------------------------------------------------------------------------
__global__ __launch_bounds__(256) void prep_kernel(
    const int* __restrict__ dst, int* __restrict__ bucketCnt, int E, int b2,
    int NB,
    const float* __restrict__ feat, unsigned short* __restrict__ featbf,
    int total8, int cb,
    const float* __restrict__ Wself, const float* __restrict__ Wneigh,
    const float* __restrict__ b_self, const float* __restrict__ b_neigh,
    const float* __restrict__ bias,
    unsigned short* __restrict__ bfrag, float* __restrict__ bb,
    const float* __restrict__ Wsp, float* __restrict__ wsoa, int pb,
    const float* __restrict__ pos, float4* __restrict__ pos4, int N)
{
    int b = blockIdx.x;
    int tid = threadIdx.x;
    if (b < b2) {
        __shared__ int cnt[MAXNB];
        for (int i = tid; i < NB; i += 256) cnt[i] = 0;
        __syncthreads();
        int e0 = b * 1024 + tid * 4;
        if (e0 + 3 < E) {
            int4 d4 = *(const int4*)(dst + e0);
            atomicAdd(&cnt[d4.x >> 7], 1);
            atomicAdd(&cnt[d4.y >> 7], 1);
            atomicAdd(&cnt[d4.z >> 7], 1);
            atomicAdd(&cnt[d4.w >> 7], 1);
        } else {
            for (int j = 0; j < 4; ++j)
                if (e0 + j < E) atomicAdd(&cnt[dst[e0 + j] >> 7], 1);
        }
        __syncthreads();
        for (int i = tid; i < NB; i += 256)
            if (cnt[i]) atomicAdd(&bucketCnt[i], cnt[i]);
    } else if (b < b2 + cb) {
        int i = (b - b2) * 256 + tid;          // handles 8 floats
        if (i < total8) {
            float4 v0 = *(const float4*)(feat + (size_t)i * 8);
            float4 v1 = *(const float4*)(feat + (size_t)i * 8 + 4);
            bf16x8 o;
            o[0] = (short)f2bf(v0.x); o[1] = (short)f2bf(v0.y);
            o[2] = (short)f2bf(v0.z); o[3] = (short)f2bf(v0.w);
            o[4] = (short)f2bf(v1.x); o[5] = (short)f2bf(v1.y);
            o[6] = (short)f2bf(v1.z); o[7] = (short)f2bf(v1.w);
            *(bf16x8*)(featbf + (size_t)i * 8) = o;
        }
    } else if (b < b2 + cb + pb) {
        int idx = (b - b2 - cb) * 256 + tid;   // 0..32767
        if (idx < 32768) {
            int j = idx & 7;
            int l = (idx >> 3) & 63;
            int f = (idx >> 9) & 7;
            int s = (idx >> 12) & 7;
            int k = s * 32 + ((l >> 4) << 3) + j;
            int c = f * 16 + (l & 15);
            float v = (k < 128) ? Wself[c * 128 + k] : Wneigh[c * 128 + (k - 128)];
            bfrag[idx] = f2bf(v);
        }
        if (idx < 128) bb[idx] = b_self[idx] + b_neigh[idx] + bias[idx];
        if (idx < 384) {
            int r = idx >> 7, dd = idx & 127;
            wsoa[idx] = Wsp[dd * 3 + r];       // wsoa[r][d]
        }
    } else {
        int i = (b - b2 - cb - pb) * 256 + tid;
        if (i < N) {
            pos4[i] = make_float4(pos[i * 3 + 0], pos[i * 3 + 1],
                                  pos[i * 3 + 2], 0.0f);
        }
    }
}

// ---------------------------------------------------------------------------
// 2) Bucket exclusive scan (1 block of 512; NB <= 512). rowptr[N]=E sentinel.
// ---------------------------------------------------------------------------
__global__ __launch_bounds__(512) void bucket_scan(
    const int* __restrict__ bucketCnt, int* __restrict__ bucketBase, int NB,
    int* __restrict__ rowptr, int N, int E)
{
    __shared__ int wsum[8];
    int tid = threadIdx.x, lane = tid & 63, w = tid >> 6;
    int v = (tid < NB) ? bucketCnt[tid] : 0;
    int x = v;
#pragma unroll
    for (int off = 1; off < 64; off <<= 1) {
        int t = __shfl_up(x, off, 64);
        if (lane >= off) x += t;
    }
    if (lane == 63) wsum[w] = x;
    __syncthreads();
    int add = 0;
#pragma unroll
    for (int ww = 0; ww < 8; ++ww) if (ww < w) add += wsum[ww];
    if (tid < NB) bucketBase[tid] = add + x - v;
    if (tid == 0) { bucketBase[NB] = E; rowptr[N] = E; }
}

// ---------------------------------------------------------------------------
// 3) binA: bucket-partition edges. WIDE blocks (1024 thr, 4096 edges) ->
//    avg chunk 10.5 records (~168B, near-full-line writes) and 4x fewer
//    global chunk reservations. Coeffs from pos4.
//    Record: {c0, c1, c2, (src<<16)|dst}
// ---------------------------------------------------------------------------
__global__ __launch_bounds__(1024) void binA_kernel(
    const int* __restrict__ dst, const int* __restrict__ src,
    const float4* __restrict__ pos4, const int* __restrict__ bucketBase,
    int* __restrict__ gcur, uint4* __restrict__ etmp, int E, int NB)
{
    __shared__ int cnt[MAXNB];
    __shared__ int cbase[MAXNB];
    int tid = threadIdx.x;
    for (int i = tid; i < NB; i += 1024) cnt[i] = 0;
    __syncthreads();

    int e0 = blockIdx.x * 4096 + tid * 4;
    int dd[4], ss[4], slot[4];
    float cc[4][3];
    int nv = min(4, E - e0);            // valid edges this thread (may be <=0)
    if (nv > 0 && nv == 4) {
        int4 d4 = *(const int4*)(dst + e0);
        int4 s4 = *(const int4*)(src + e0);
        dd[0] = d4.x; dd[1] = d4.y; dd[2] = d4.z; dd[3] = d4.w;
        ss[0] = s4.x; ss[1] = s4.y; ss[2] = s4.z; ss[3] = s4.w;
    } else if (nv > 0) {
#pragma unroll
        for (int j = 0; j < 4; ++j) {
            dd[j] = (j < nv) ? dst[e0 + j] : 0;
            ss[j] = (j < nv) ? src[e0 + j] : 0;
        }
    }
    if (nv > 0) {
#pragma unroll
        for (int j = 0; j < 4; ++j) {
            if (j < nv) {
                slot[j] = atomicAdd(&cnt[dd[j] >> 7], 1);
                float4 pd = pos4[dd[j]];
                float4 ps = pos4[ss[j]];
                float r0 = pd.x - ps.x;
                float r1 = pd.y - ps.y;
                float r2 = pd.z - ps.z;
                float inv = 1.0f / (sqrtf(r0 * r0 + r1 * r1 + r2 * r2) + EPS_SCALE);
                cc[j][0] = (r0 + 1.0f) * inv;
                cc[j][1] = (r1 + 1.0f) * inv;
                cc[j][2] = (r2 + 1.0f) * inv;
            }
        }
    }
    __syncthreads();
    for (int i = tid; i < NB; i += 1024)
        cbase[i] = cnt[i] ? atomicAdd(&gcur[i], cnt[i]) : 0;
    __syncthreads();
    if (nv > 0) {
#pragma unroll
        for (int j = 0; j < 4; ++j) {
            if (j < nv) {
                int bk = dd[j] >> 7;
                int p = bucketBase[bk] + cbase[bk] + slot[j];
                etmp[p] = make_uint4(__float_as_uint(cc[j][0]),
                                     __float_as_uint(cc[j][1]),
                                     __float_as_uint(cc[j][2]),
                                     ((unsigned)ss[j] << 16) | (unsigned)dd[j]);
            }
        }
    }
}

// ---------------------------------------------------------------------------
// 4) binB: one block per bucket. Node counts, scan, cursors all in LDS
//    (zero global atomics). Emits rowptr + node-ordered ecoef.
// ---------------------------------------------------------------------------
__global__ __launch_bounds__(256) void binB_kernel(
    const uint4* __restrict__ etmp, const int* __restrict__ bucketBase,
    float4* __restrict__ ecoef, int* __restrict__ rowptr, int N)
{
    __shared__ int ncnt[BN];
    __shared__ int noff[BN];
    __shared__ int wsum[4];
    int b = blockIdx.x, tid = threadIdx.x;
    int start = bucketBase[b];
    int endb  = bucketBase[b + 1];

    if (tid < BN) ncnt[tid] = 0;
    __syncthreads();
    for (int i = start + tid; i < endb; i += 256)
        atomicAdd(&ncnt[etmp[i].w & (BN - 1)], 1);
    __syncthreads();

    int lane = tid & 63, w = tid >> 6;
    int v = (tid < BN) ? ncnt[tid] : 0;
    int x = v;
#pragma unroll
    for (int off = 1; off < 64; off <<= 1) {
        int t = __shfl_up(x, off, 64);
        if (lane >= off) x += t;
    }
    if (lane == 63) wsum[w] = x;
    __syncthreads();
    int add = 0;
#pragma unroll
    for (int ww = 0; ww < 4; ++ww) if (ww < w) add += wsum[ww];
    int excl = add + x - v;
    if (tid < BN) {
        noff[tid] = excl;
        int node = b * BN + tid;
        if (node < N) rowptr[node] = start + excl;
    }
    __syncthreads();

    for (int i = start + tid; i < endb; i += 256) {
        uint4 r = etmp[i];
        int dl = (int)(r.w & (BN - 1));
        int p = atomicAdd(&noff[dl], 1);
        ecoef[start + p] = make_float4(__uint_as_float(r.x),
                                       __uint_as_float(r.y),
                                       __uint_as_float(r.z),
                                       __int_as_float((int)(r.w >> 16)));
    }
}

// ---------------------------------------------------------------------------
// 5) Gather (r16-proven optimum): 2 nodes/wave, 2 edge slots/node, 2x unroll
//    -> 8 chains/wave (measured MLP optimum). Packed f32x2 math (pk_fma).
// ---------------------------------------------------------------------------
#define EDGE_FMA2(QC, FU)                                                        \
    do {                                                                         \
        f32x2 c0v = {QC.x, QC.x};                                                \
        f32x2 c1v = {QC.y, QC.y};                                                \
        f32x2 c2v = {QC.z, QC.z};                                                \
        unsigned fw0 = FU.x, fw1 = FU.y, fw2 = FU.z, fw3 = FU.w;                 \
        f32x2 fv0 = {__uint_as_float(fw0 << 16),                                 \
                     __uint_as_float(fw0 & 0xffff0000u)};                        \
        f32x2 fv1 = {__uint_as_float(fw1 << 16),                                 \
                     __uint_as_float(fw1 & 0xffff0000u)};                        \
        f32x2 fv2 = {__uint_as_float(fw2 << 16),                                 \
                     __uint_as_float(fw2 & 0xffff0000u)};                        \
        f32x2 fv3 = {__uint_as_float(fw3 << 16),                                 \
                     __uint_as_float(fw3 & 0xffff0000u)};                        \
        f32x2 g0 = __builtin_elementwise_fma(c0v, w0v[0],                        \
                   __builtin_elementwise_fma(c1v, w1v[0],                        \
                   __builtin_elementwise_fma(c2v, w2v[0], bv[0])));              \
        f32x2 g1 = __builtin_elementwise_fma(c0v, w0v[1],                        \
                   __builtin_elementwise_fma(c1v, w1v[1],                        \
                   __builtin_elementwise_fma(c2v, w2v[1], bv[1])));              \
        f32x2 g2 = __builtin_elementwise_fma(c0v, w0v[2],                        \
                   __builtin_elementwise_fma(c1v, w1v[2],                        \
                   __builtin_elementwise_fma(c2v, w2v[2], bv[2])));              \
        f32x2 g3 = __builtin_elementwise_fma(c0v, w0v[3],                        \
                   __builtin_elementwise_fma(c1v, w1v[3],                        \
                   __builtin_elementwise_fma(c2v, w2v[3], bv[3])));              \
        g0 = __builtin_elementwise_max(g0, g0 * 0.01f);                          \
        g1 = __builtin_elementwise_max(g1, g1 * 0.01f);                          \
        g2 = __builtin_elementwise_max(g2, g2 * 0.01f);                          \
        g3 = __builtin_elementwise_max(g3, g3 * 0.01f);                          \
        acc[0] = __builtin_elementwise_fma(g0, fv0, acc[0]);                     \
        acc[1] = __builtin_elementwise_fma(g1, fv1, acc[1]);                     \
        acc[2] = __builtin_elementwise_fma(g2, fv2, acc[2]);                     \
        acc[3] = __builtin_elementwise_fma(g3, fv3, acc[3]);                     \
    } while (0)

__global__ __launch_bounds__(256) void gather_kernel(
    const unsigned short* __restrict__ featbf,
    const float4* __restrict__ ecoef,
    const int*   __restrict__ rowptr,
    const float* __restrict__ wsoa,  // [3][128]
    const float* __restrict__ bsp,   // [128]
    unsigned short* __restrict__ hmbf,  // [N][128]
    int N, int nwaves)
{
    int gw   = (blockIdx.x * 256 + threadIdx.x) >> 6;
    int lane = threadIdx.x & 63;
    int half = lane >> 5;          // which node of the pair
    int e2   = (lane >> 4) & 1;    // edge slot within the node
    int sl   = lane & 15;
    int d    = sl * 8;

    f32x2 w0v[4], w1v[4], w2v[4], bv[4];
#pragma unroll
    for (int g = 0; g < 4; ++g) {
        w0v[g] = *(const f32x2*)(wsoa + d + g * 2);
        w1v[g] = *(const f32x2*)(wsoa + 128 + d + g * 2);
        w2v[g] = *(const f32x2*)(wsoa + 256 + d + g * 2);
        bv[g]  = *(const f32x2*)(bsp + d + g * 2);
    }

    const unsigned short* fb = featbf + d;
    int stride = nwaves * 2;

    for (int vp = gw * 2; vp < N; vp += stride) {
        int v = vp + half;
        int start = 0, end = 0;
        if (v < N) { start = rowptr[v]; end = rowptr[v + 1]; }

        f32x2 acc[4];
#pragma unroll
        for (int g = 0; g < 4; ++g) acc[g] = (f32x2)0.0f;

        int i = start + e2;
        for (; i + 2 < end; i += 4) {
            float4 qcA = ecoef[i];
            float4 qcB = ecoef[i + 2];
            uint4 fA = *(const uint4*)(fb + (size_t)__float_as_int(qcA.w) * DIN);
            uint4 fB = *(const uint4*)(fb + (size_t)__float_as_int(qcB.w) * DIN);
            EDGE_FMA2(qcA, fA);
            EDGE_FMA2(qcB, fB);
        }
        if (i < end) {
            float4 qcA = ecoef[i];
            uint4 fA = *(const uint4*)(fb + (size_t)__float_as_int(qcA.w) * DIN);
            EDGE_FMA2(qcA, fA);
        }

        // combine the two edge slots (within the 32-lane half)
#pragma unroll
        for (int g = 0; g < 4; ++g) {
            acc[g].x += __shfl_xor(acc[g].x, 16);
            acc[g].y += __shfl_xor(acc[g].y, 16);
        }

        if (e2 == 0 && v < N) {
            float invd = 1.0f / fmaxf((float)(end - start), 1.0f);
            bf16x8 o;
#pragma unroll
            for (int g = 0; g < 4; ++g) {
                o[g * 2 + 0] = (short)f2bf(acc[g].x * invd);
                o[g * 2 + 1] = (short)f2bf(acc[g].y * invd);
            }
            *(bf16x8*)(hmbf + (size_t)v * DIN + d) = o;
        }
    }
}

// ---------------------------------------------------------------------------
// 6) Node GEMM via MFMA: out = lrelu([featbf | hmbf] @ Wc^T + bb)
// ---------------------------------------------------------------------------
__global__ __launch_bounds__(256) void node_mfma_kernel(
    const unsigned short* __restrict__ featbf,
    const unsigned short* __restrict__ hmbf,
    const unsigned short* __restrict__ bfrag,
    const float* __restrict__ bb,
    float* __restrict__ out, int N)
{
    int wave = threadIdx.x >> 6;
    int lane = threadIdx.x & 63;
    int r0   = blockIdx.x * 64 + wave * 16;
    int row  = r0 + (lane & 15);
    bool rowok = row < N;
    int kb = (lane >> 4) << 3;

    f32x4 acc[8];
#pragma unroll
    for (int f = 0; f < 8; ++f) acc[f] = (f32x4)0.0f;

#pragma unroll
    for (int s = 0; s < 8; ++s) {
        bf16x8 a = (bf16x8)(short)0;
        if (rowok) {
            const unsigned short* base =
                (s < 4 ? featbf : hmbf) + (size_t)row * DIN + (s & 3) * 32 + kb;
            a = *(const bf16x8*)base;
        }
#pragma unroll
        for (int f = 0; f < 8; ++f) {
            bf16x8 b = *(const bf16x8*)(bfrag + ((((s * 8 + f) * 64) + lane) * 8));
            acc[f] = __builtin_amdgcn_mfma_f32_16x16x32_bf16(a, b, acc[f], 0, 0, 0);
        }
    }

    int crow = r0 + ((lane >> 4) << 2);
    int col  = lane & 15;
#pragma unroll
    for (int f = 0; f < 8; ++f) {
        int c = f * 16 + col;
        float bbv = bb[c];
#pragma unroll
        for (int r = 0; r < 4; ++r) {
            int rr = crow + r;
            if (rr < N) out[(size_t)rr * DOUT + c] = lrelu(acc[f][r] + bbv);
        }
    }
}

// ---------------------------------------------------------------------------
extern "C" void kernel_launch(void* const* d_in, const int* in_sizes, int n_in,
                              void* d_out, int out_size, void* d_ws, size_t ws_size,
                              hipStream_t stream)
{
    const float* feat    = (const float*)d_in[0];
    const float* pos     = (const float*)d_in[1];
    const int*   src     = (const int*)  d_in[2];
    const int*   dst     = (const int*)  d_in[3];
    const float* Wsp     = (const float*)d_in[4];
    const float* bsp     = (const float*)d_in[5];
    const float* Wneigh  = (const float*)d_in[6];
    const float* b_neigh = (const float*)d_in[7];
    const float* Wself   = (const float*)d_in[8];
    const float* b_self  = (const float*)d_in[9];
    const float* bias    = (const float*)d_in[10];

    int N = in_sizes[0] / DIN;
    int E = in_sizes[2];
    int NB = (N + BN - 1) / BN;   // buckets (391 for N=50000; <= 512)

    // Workspace layout (all 16B aligned):
    // featbf [N*128 u16] | hmbf [N*128 u16] | ecoef [E f4] | etmp [E u4]
    // | pos4 [N f4] | bfrag [32768 u16] | bb [128 f32] | wsoa [384 f32]
    // | bucketCnt [512] | gcur [512] | bucketBase [520] | rowptr [N+4]
    char* p = (char*)d_ws;
    unsigned short* featbf = (unsigned short*)p; p += (size_t)N * DIN * 2;
    unsigned short* hmbf   = (unsigned short*)p; p += (size_t)N * DIN * 2;
    float4* ecoef          = (float4*)p;         p += (size_t)E * 16;
    uint4* etmp            = (uint4*)p;          p += (size_t)E * 16;
    float4* pos4           = (float4*)p;         p += (size_t)N * 16;
    unsigned short* bfrag  = (unsigned short*)p; p += 32768 * 2;
    float* bb              = (float*)p;          p += 128 * 4;
    float* wsoa            = (float*)p;          p += 384 * 4;
    int* bucketCnt         = (int*)p;            p += 512 * 4;
    int* gcur              = (int*)p;            p += 512 * 4;
    int* bucketBase        = (int*)p;            p += 520 * 4;
    int* rowptr            = (int*)p;

    // zero bucketCnt + gcur (adjacent, 4KB)
    hipMemsetAsync(bucketCnt, 0, 1024 * sizeof(int), stream);

    int b2 = (E + 1023) / 1024;          // bucket-count blocks (prep)
    int ba = (E + 4095) / 4096;          // binA blocks (1024 thr, 4096 edges)
    int cb = (N * 16 + 255) / 256;       // convert blocks (N*128/8 threads)
    int pb = 129;                        // pack blocks
    int qb = (N + 255) / 256;            // pos4 blocks
    prep_kernel<<<b2 + cb + pb + qb, 256, 0, stream>>>(
        dst, bucketCnt, E, b2, NB, feat, featbf, N * 16, cb,
        Wself, Wneigh, b_self, b_neigh, bias, bfrag, bb, Wsp, wsoa, pb,
        pos, pos4, N);

    bucket_scan<<<1, 512, 0, stream>>>(bucketCnt, bucketBase, NB, rowptr, N, E);

    binA_kernel<<<ba, 1024, 0, stream>>>(dst, src, pos4, bucketBase, gcur,
                                         etmp, E, NB);
    binB_kernel<<<NB, 256, 0, stream>>>(etmp, bucketBase, ecoef, rowptr, N);

    int gblocks = 2048;
    gather_kernel<<<gblocks, 256, 0, stream>>>(featbf, ecoef, rowptr, wsoa, bsp,
                                               hmbf, N, gblocks * 4);

    node_mfma_kernel<<<(N + 63) / 64, 256, 0, stream>>>(featbf, hmbf, bfrag, bb,
                                                        (float*)d_out, N);
}